// Round 4
// baseline (1046.711 us; speedup 1.0000x reference)
//
#include <hip/hip_runtime.h>

#define BSZ 2
#define NTOK 2048
#define NHEAD 8
#define DKH 16
#define DMODEL 128

// Swizzled float4 index for LDS tiles laid out [cols][16 floats].
// Row stride = 64B = 4 float4. Permute the 8 16B-granules inside each 128B
// col-pair: granule' = granule ^ ((col>>1)&7). Linear-granule closed form:
// g ^ ((g>>3)&7). Bijective (XOR key from untouched high bits).
__device__ __forceinline__ int swz(int col, int q4) {
  return ((col >> 1) << 3) | ((((col & 1) << 2) | q4) ^ ((col >> 1) & 7));
}
__device__ __forceinline__ int swzg(int g) { return g ^ ((g >> 3) & 7); }

__device__ __forceinline__ float dot16(const float (&q)[16], const float4& k0,
                                       const float4& k1, const float4& k2, const float4& k3) {
  float a = fmaf(q[3], k0.w, fmaf(q[2], k0.z, fmaf(q[1], k0.y, q[0] * k0.x)));
  float b = fmaf(q[7], k1.w, fmaf(q[6], k1.z, fmaf(q[5], k1.y, q[4] * k1.x)));
  float c = fmaf(q[11], k2.w, fmaf(q[10], k2.z, fmaf(q[9], k2.y, q[8] * k2.x)));
  float d = fmaf(q[15], k3.w, fmaf(q[14], k3.z, fmaf(q[13], k3.y, q[12] * k3.x)));
  return (a + b) + (c + d);
}

// ---------------- QKV projection: y = x @ W^T + b -> ws as [b][h][n][dk] ----------------
// grid = (128 row-tiles, 3 wtypes), block = 256 (4 waves). Tile: 32 rows x 128 outs,
// 4x4 per thread. v2: NO W LDS staging (was 64KB -> 2 waves/SIMD, latency-bound).
// W cols read straight from global: 64KB/matrix stays L1/L2-resident, total L2
// traffic ~24MB @ 34TB/s = negligible. LDS now 16KB -> many blocks/CU, ~60 VGPR.
__global__ __launch_bounds__(256) void qkv_proj_kernel(
    const float* __restrict__ x,
    const float* __restrict__ Wq, const float* __restrict__ bq,
    const float* __restrict__ Wk, const float* __restrict__ bk,
    const float* __restrict__ Wv, const float* __restrict__ bv,
    float* __restrict__ ws)
{
  __shared__ float4 sX4[32 * 32];   // [32 rows][32 float4], swizzled, 16KB
  const float *W, *bias;
  float* outp;
  if (blockIdx.y == 0)      { W = Wq; bias = bq; outp = ws; }
  else if (blockIdx.y == 1) { W = Wk; bias = bk; outp = ws + (size_t)BSZ * NTOK * DMODEL; }
  else                      { W = Wv; bias = bv; outp = ws + (size_t)2 * BSZ * NTOK * DMODEL; }

  const int t = threadIdx.x;
  #pragma unroll
  for (int k = 0; k < 4; k++) {
    int f4 = t + 256 * k;
    int r = f4 >> 5, i4 = f4 & 31;
    sX4[r * 32 + (i4 ^ (r & 7))] = ((const float4*)x)[(size_t)blockIdx.x * 1024 + f4];
  }
  __syncthreads();

  const int c0 = t & 31;   // cols c0 + 32*cc
  const int r0 = t >> 5;   // rows r0 + 8*rr   (r0 in 0..7 so r0&7 == r0)
  const float4* W4 = (const float4*)W;
  float acc[4][4];
  #pragma unroll
  for (int i = 0; i < 4; i++)
    #pragma unroll
    for (int j = 0; j < 4; j++) acc[i][j] = 0.f;

  #pragma unroll 8
  for (int i0 = 0; i0 < 32; i0++) {
    float4 xr[4], wc[4];
    #pragma unroll
    for (int rr = 0; rr < 4; rr++) xr[rr] = sX4[(r0 + 8 * rr) * 32 + (i0 ^ r0)];
    #pragma unroll
    for (int cc = 0; cc < 4; cc++) wc[cc] = W4[(c0 + 32 * cc) * 32 + i0];
    #pragma unroll
    for (int rr = 0; rr < 4; rr++)
      #pragma unroll
      for (int cc = 0; cc < 4; cc++) {
        acc[rr][cc] = fmaf(xr[rr].x, wc[cc].x, acc[rr][cc]);
        acc[rr][cc] = fmaf(xr[rr].y, wc[cc].y, acc[rr][cc]);
        acc[rr][cc] = fmaf(xr[rr].z, wc[cc].z, acc[rr][cc]);
        acc[rr][cc] = fmaf(xr[rr].w, wc[cc].w, acc[rr][cc]);
      }
  }

  #pragma unroll
  for (int cc = 0; cc < 4; cc++) {
    const int c = c0 + 32 * cc;
    const float bv_ = bias[c];
    const int hh = c >> 4, d = c & 15;
    #pragma unroll
    for (int rr = 0; rr < 4; rr++) {
      const int rg = blockIdx.x * 32 + r0 + 8 * rr;
      const int bb = rg >> 11, n = rg & (NTOK - 1);
      outp[(((size_t)(bb * NHEAD + hh)) * NTOK + n) * DKH + d] = acc[rr][cc] + bv_;
    }
  }
}

// ---------------- Fused attention ----------------
// 256 blocks, 1/CU. XCD-aware remap: phys%8 = XCD (HW round-robin), XCD x gets
// groups G = x*4 + slot>>3 (G = rc*2+b), h = slot&7 => the 16 blocks sharing an
// sp row-window / 8 sharing adj[b] rows co-reside on ONE XCD's L2.
// v2: block = 1024 threads (16 waves) -> 4 waves/SIMD (was 2; VALUBusy was 15%,
// occupancy 23%, nothing saturated = latency-bound). Wave owns 2 rows x 4 batches.
// K resident in LDS (128KB, swizzled); V double-buffered 256-col chunks (2x16KB);
// chunk-0 loads issue before QK (hidden), chunk c+1 loads during chunk c's PV.
// LDS = 160KB (HW max). VGPR capped at 128 via launch_bounds for 4 waves/SIMD.
// No-max softmax (scores <= ~7): p held in registers for the whole row => single
// pass writes normalized attn (nontemporal) and accumulates PV.
__global__ __launch_bounds__(1024, 4) void attn_fused_kernel(
    const float* __restrict__ qw, const float* __restrict__ kw, const float* __restrict__ vw,
    const int* __restrict__ adj, const float* __restrict__ sp,
    float* __restrict__ out, float* __restrict__ attn)
{
  __shared__ float sK[NTOK * DKH];        // 128KB
  __shared__ float sV[2][256 * DKH];      // 2 x 16KB double buffer
  float4* sK4 = (float4*)sK;

  const int phys = blockIdx.x;
  const int xcd  = phys & 7;
  const int slot = phys >> 3;             // 0..31
  const int G    = xcd * 4 + (slot >> 3); // 0..31 = rc*2 + b
  const int h    = slot & 7;
  const int rc   = G >> 1;
  const int b    = G & 1;
  const int bh   = b * NHEAD + h;
  const int t = threadIdx.x, lane = t & 63, w = t >> 6;

  const float*  Qp  = qw + (size_t)bh * NTOK * DKH;
  const float4* Kp4 = (const float4*)(kw + (size_t)bh * NTOK * DKH);
  const float4* Vp4 = (const float4*)(vw + (size_t)bh * NTOK * DKH);
  const int* adjb = adj + (size_t)b * NTOK * NTOK;
  float* attnb = attn + (size_t)bh * NTOK * NTOK;

  // Stage K for all 2048 cols (coalesced float4 reads, swizzled ds_write_b128)
  #pragma unroll
  for (int kk = 0; kk < 8; kk++) {
    int f4 = t + 1024 * kk;               // 8192 float4 total
    sK4[swzg(f4)] = Kp4[f4];
  }
  __syncthreads();

  for (int batch = 0; batch < 4; batch++) {
    const int r0 = rc * 128 + batch * 32 + w * 2;
    const int r1 = r0 + 1;

    // Issue V chunk-0 load now; completes under the whole QK phase.
    float4 pv = Vp4[t];

    float q0[16], q1[16];
    {
      const float4* q4a = (const float4*)(Qp + r0 * DKH);
      const float4* q4b = (const float4*)(Qp + r1 * DKH);
      float4 a0 = q4a[0], a1 = q4a[1], a2 = q4a[2], a3 = q4a[3];
      float4 c0v = q4b[0], c1 = q4b[1], c2 = q4b[2], c3 = q4b[3];
      q0[0]=a0.x; q0[1]=a0.y; q0[2]=a0.z; q0[3]=a0.w;
      q0[4]=a1.x; q0[5]=a1.y; q0[6]=a1.z; q0[7]=a1.w;
      q0[8]=a2.x; q0[9]=a2.y; q0[10]=a2.z; q0[11]=a2.w;
      q0[12]=a3.x; q0[13]=a3.y; q0[14]=a3.z; q0[15]=a3.w;
      q1[0]=c0v.x; q1[1]=c0v.y; q1[2]=c0v.z; q1[3]=c0v.w;
      q1[4]=c1.x; q1[5]=c1.y; q1[6]=c1.z; q1[7]=c1.w;
      q1[8]=c2.x; q1[9]=c2.y; q1[10]=c2.z; q1[11]=c2.w;
      q1[12]=c3.x; q1[13]=c3.y; q1[14]=c3.z; q1[15]=c3.w;
    }

    const float* sp0 = sp + (size_t)r0 * NTOK;
    const float* sp1 = sp + (size_t)r1 * NTOK;
    const int* a0p = adjb + (size_t)r0 * NTOK;
    const int* a1p = adjb + (size_t)r1 * NTOK;

    float p0[32], p1[32];
    float l0 = 0.f, l1 = 0.f;
    #pragma unroll
    for (int j = 0; j < 32; j++) {
      const int col = lane + 64 * j;
      const float4 k0 = sK4[swz(col, 0)], k1 = sK4[swz(col, 1)];
      const float4 k2 = sK4[swz(col, 2)], k3 = sK4[swz(col, 3)];
      float s0 = dot16(q0, k0, k1, k2, k3);
      float s1 = dot16(q1, k0, k1, k2, k3);
      float e0 = sp0[col]; if (col == r0) e0 = 0.f;   // sp_enc diagonal zeroed
      float e1 = sp1[col]; if (col == r1) e1 = 0.f;
      s0 = fmaf(s0, 0.25f, e0);                        // /sqrt(16)
      s1 = fmaf(s1, 0.25f, e1);
      const float pe0 = (a0p[col] != 0) ? __expf(s0) : 0.f;  // mask==exp(-1e10)==0
      const float pe1 = (a1p[col] != 0) ? __expf(s1) : 0.f;
      p0[j] = pe0; p1[j] = pe1;
      l0 += pe0; l1 += pe1;
    }

    #pragma unroll
    for (int m = 1; m < 64; m <<= 1) {
      l0 += __shfl_xor(l0, m, 64);
      l1 += __shfl_xor(l1, m, 64);
    }
    const float rl0 = 1.0f / l0, rl1 = 1.0f / l1;

    // Normalize IN PLACE: both the attn store and PV use softmax probabilities.
    // attn is write-once: nontemporal, don't pollute L2.
    float* A0 = attnb + (size_t)r0 * NTOK;
    float* A1 = attnb + (size_t)r1 * NTOK;
    #pragma unroll
    for (int j = 0; j < 32; j++) {
      p0[j] *= rl0;
      p1[j] *= rl1;
      __builtin_nontemporal_store(p0[j], &A0[lane + 64 * j]);
      __builtin_nontemporal_store(p1[j], &A1[lane + 64 * j]);
    }

    float o0[16], o1[16];
    #pragma unroll
    for (int d = 0; d < 16; d++) { o0[d] = 0.f; o1[d] = 0.f; }

    // Write chunk 0 (loaded above). buf0's last readers sat behind prev vc==6's
    // barrier, so it is free to overwrite.
    ((float4*)sV[0])[swzg(t)] = pv;
    __syncthreads();

    #pragma unroll
    for (int vc = 0; vc < 8; vc++) {
      float4 nv;
      if (vc < 7) nv = Vp4[(vc + 1) * 1024 + t];   // issue next chunk early
      const float4* sV4 = (const float4*)sV[vc & 1];
      #pragma unroll
      for (int jj = 0; jj < 4; jj++) {
        const int j = vc * 4 + jj;
        const int cl = lane + 64 * jj;
        const float4 v0 = sV4[swz(cl, 0)], v1 = sV4[swz(cl, 1)];
        const float4 v2 = sV4[swz(cl, 2)], v3 = sV4[swz(cl, 3)];
        const float a0 = p0[j], a1 = p1[j];
        o0[0] = fmaf(a0, v0.x, o0[0]);  o0[1] = fmaf(a0, v0.y, o0[1]);
        o0[2] = fmaf(a0, v0.z, o0[2]);  o0[3] = fmaf(a0, v0.w, o0[3]);
        o0[4] = fmaf(a0, v1.x, o0[4]);  o0[5] = fmaf(a0, v1.y, o0[5]);
        o0[6] = fmaf(a0, v1.z, o0[6]);  o0[7] = fmaf(a0, v1.w, o0[7]);
        o0[8] = fmaf(a0, v2.x, o0[8]);  o0[9] = fmaf(a0, v2.y, o0[9]);
        o0[10] = fmaf(a0, v2.z, o0[10]); o0[11] = fmaf(a0, v2.w, o0[11]);
        o0[12] = fmaf(a0, v3.x, o0[12]); o0[13] = fmaf(a0, v3.y, o0[13]);
        o0[14] = fmaf(a0, v3.z, o0[14]); o0[15] = fmaf(a0, v3.w, o0[15]);
        o1[0] = fmaf(a1, v0.x, o1[0]);  o1[1] = fmaf(a1, v0.y, o1[1]);
        o1[2] = fmaf(a1, v0.z, o1[2]);  o1[3] = fmaf(a1, v0.w, o1[3]);
        o1[4] = fmaf(a1, v1.x, o1[4]);  o1[5] = fmaf(a1, v1.y, o1[5]);
        o1[6] = fmaf(a1, v1.z, o1[6]);  o1[7] = fmaf(a1, v1.w, o1[7]);
        o1[8] = fmaf(a1, v2.x, o1[8]);  o1[9] = fmaf(a1, v2.y, o1[9]);
        o1[10] = fmaf(a1, v2.z, o1[10]); o1[11] = fmaf(a1, v2.w, o1[11]);
        o1[12] = fmaf(a1, v3.x, o1[12]); o1[13] = fmaf(a1, v3.y, o1[13]);
        o1[14] = fmaf(a1, v3.z, o1[14]); o1[15] = fmaf(a1, v3.w, o1[15]);
      }
      if (vc < 7) {
        ((float4*)sV[(vc + 1) & 1])[swzg(t)] = nv;
        __syncthreads();
      }
    }

    // cross-lane reduce the 2x16 partial outputs, lane 0 stores
    #pragma unroll
    for (int m = 1; m < 64; m <<= 1) {
      #pragma unroll
      for (int d = 0; d < 16; d++) {
        o0[d] += __shfl_xor(o0[d], m, 64);
        o1[d] += __shfl_xor(o1[d], m, 64);
      }
    }
    if (lane == 0) {
      #pragma unroll
      for (int d = 0; d < 16; d++) {
        // out layout: (b, n, dk, h) flattened -> [b][n][d*8 + h]
        out[((size_t)b * NTOK + r0) * DMODEL + d * NHEAD + h] = o0[d];
        out[((size_t)b * NTOK + r1) * DMODEL + d * NHEAD + h] = o1[d];
      }
    }
  }
}

extern "C" void kernel_launch(void* const* d_in, const int* in_sizes, int n_in,
                              void* d_out, int out_size, void* d_ws, size_t ws_size,
                              hipStream_t stream) {
  const float* x   = (const float*)d_in[0];
  const int*   adj = (const int*)d_in[1];
  const float* sp  = (const float*)d_in[2];
  const float* Wq  = (const float*)d_in[3];
  const float* bq  = (const float*)d_in[4];
  const float* Wk  = (const float*)d_in[5];
  const float* bk  = (const float*)d_in[6];
  const float* Wv  = (const float*)d_in[7];
  const float* bv  = (const float*)d_in[8];

  float* out  = (float*)d_out;
  float* attn = out + (size_t)BSZ * NTOK * DMODEL;
  float* ws   = (float*)d_ws;    // Q,K,V: 3 * 524288 floats = 6 MB

  qkv_proj_kernel<<<dim3(BSZ * NTOK / 32, 3), dim3(256), 0, stream>>>(
      x, Wq, bq, Wk, bk, Wv, bv, ws);

  const float* qws = ws;
  const float* kws = ws + (size_t)BSZ * NTOK * DMODEL;
  const float* vws = ws + (size_t)2 * BSZ * NTOK * DMODEL;
  attn_fused_kernel<<<dim3(256), dim3(1024), 0, stream>>>(
      qws, kws, vws, adj, sp, out, attn);
}

// Round 5
// 1029.864 us; speedup vs baseline: 1.0164x; 1.0164x over previous
//
#include <hip/hip_runtime.h>

#define BSZ 2
#define NTOK 2048
#define NHEAD 8
#define DKH 16
#define DMODEL 128

// Swizzled float4 index for LDS tiles laid out [cols][16 floats].
// Row stride = 64B = 4 float4. Permute the 8 16B-granules inside each 128B
// col-pair: granule' = granule ^ ((col>>1)&7). Linear-granule closed form:
// g ^ ((g>>3)&7). Bijective (XOR key from untouched high bits).
__device__ __forceinline__ int swz(int col, int q4) {
  return ((col >> 1) << 3) | ((((col & 1) << 2) | q4) ^ ((col >> 1) & 7));
}
__device__ __forceinline__ int swzg(int g) { return g ^ ((g >> 3) & 7); }

__device__ __forceinline__ float dot16(const float (&q)[16], const float4& k0,
                                       const float4& k1, const float4& k2, const float4& k3) {
  float a = fmaf(q[3], k0.w, fmaf(q[2], k0.z, fmaf(q[1], k0.y, q[0] * k0.x)));
  float b = fmaf(q[7], k1.w, fmaf(q[6], k1.z, fmaf(q[5], k1.y, q[4] * k1.x)));
  float c = fmaf(q[11], k2.w, fmaf(q[10], k2.z, fmaf(q[9], k2.y, q[8] * k2.x)));
  float d = fmaf(q[15], k3.w, fmaf(q[14], k3.z, fmaf(q[13], k3.y, q[12] * k3.x)));
  return (a + b) + (c + d);
}

// ---------------- QKV projection: y = x @ W^T + b -> ws as [b][h][n][dk] ----------------
// grid = (128 row-tiles, 3 wtypes), block = 256. Tile: 32 rows x 128 outs, 4x4/thread.
// W staged in LDS (64KB, swizzled, coalesced) + X tile 16KB -> 80KB, 2 blocks/CU.
__global__ __launch_bounds__(256) void qkv_proj_kernel(
    const float* __restrict__ x,
    const float* __restrict__ Wq, const float* __restrict__ bq,
    const float* __restrict__ Wk, const float* __restrict__ bk,
    const float* __restrict__ Wv, const float* __restrict__ bv,
    float* __restrict__ ws)
{
  __shared__ float sW[DMODEL * 32 * 4];   // [128][32] float4, swizzled, 64KB
  __shared__ float sX[32 * 32 * 4];       // [32][32]  float4, swizzled, 16KB
  const float *W, *bias;
  float* outp;
  if (blockIdx.y == 0)      { W = Wq; bias = bq; outp = ws; }
  else if (blockIdx.y == 1) { W = Wk; bias = bk; outp = ws + (size_t)BSZ * NTOK * DMODEL; }
  else                      { W = Wv; bias = bv; outp = ws + (size_t)2 * BSZ * NTOK * DMODEL; }

  const int t = threadIdx.x;
  float4* sW4 = (float4*)sW;
  float4* sX4 = (float4*)sX;
  #pragma unroll
  for (int k = 0; k < 16; k++) {
    int f4 = t + 256 * k;
    int o = f4 >> 5, i4 = f4 & 31;
    sW4[o * 32 + (i4 ^ (o & 7))] = ((const float4*)W)[f4];
  }
  #pragma unroll
  for (int k = 0; k < 4; k++) {
    int f4 = t + 256 * k;
    int r = f4 >> 5, i4 = f4 & 31;
    sX4[r * 32 + (i4 ^ (r & 7))] = ((const float4*)x)[(size_t)blockIdx.x * 1024 + f4];
  }
  __syncthreads();

  const int c0 = t & 31;   // cols c0 + 32*cc  (stride-1 across lanes -> swizzle works)
  const int r0 = t >> 5;   // rows r0 + 8*rr
  float acc[4][4];
  #pragma unroll
  for (int i = 0; i < 4; i++)
    #pragma unroll
    for (int j = 0; j < 4; j++) acc[i][j] = 0.f;

  #pragma unroll 8
  for (int i0 = 0; i0 < 32; i0++) {
    float4 xr[4], wc[4];
    #pragma unroll
    for (int rr = 0; rr < 4; rr++) xr[rr] = sX4[(r0 + 8 * rr) * 32 + (i0 ^ (r0 & 7))];
    #pragma unroll
    for (int cc = 0; cc < 4; cc++) wc[cc] = sW4[(c0 + 32 * cc) * 32 + (i0 ^ (c0 & 7))];
    #pragma unroll
    for (int rr = 0; rr < 4; rr++)
      #pragma unroll
      for (int cc = 0; cc < 4; cc++) {
        acc[rr][cc] = fmaf(xr[rr].x, wc[cc].x, acc[rr][cc]);
        acc[rr][cc] = fmaf(xr[rr].y, wc[cc].y, acc[rr][cc]);
        acc[rr][cc] = fmaf(xr[rr].z, wc[cc].z, acc[rr][cc]);
        acc[rr][cc] = fmaf(xr[rr].w, wc[cc].w, acc[rr][cc]);
      }
  }

  #pragma unroll
  for (int cc = 0; cc < 4; cc++) {
    const int c = c0 + 32 * cc;
    const float bv_ = bias[c];
    const int hh = c >> 4, d = c & 15;
    #pragma unroll
    for (int rr = 0; rr < 4; rr++) {
      const int rg = blockIdx.x * 32 + r0 + 8 * rr;
      const int bb = rg >> 11, n = rg & (NTOK - 1);
      outp[(((size_t)(bb * NHEAD + hh)) * NTOK + n) * DKH + d] = acc[rr][cc] + bv_;
    }
  }
}

// ---------------- Fused attention ----------------
// 256 blocks, 1/CU. XCD-aware remap: phys%8 = XCD (HW round-robin), XCD x gets
// groups G = x*4 + slot>>3 (G = rc*2+b), h = slot&7 => the 16 blocks sharing an
// sp row-window / 8 sharing adj[b] rows co-reside on ONE XCD's L2.
// block = 1024 threads (16 waves) -> 4 waves/SIMD. launch_bounds(1024,1):
// launchability caps VGPR at 2048/16 = 128, which is exactly the live-state
// demand (round 3 compiled to 128) -> no spills. Round 4's (1024,4) crushed
// VGPR to 64 and spilled ~860MB to scratch (FETCH 312->645, WRITE 331->842MB).
// K resident in LDS (128KB, swizzled); V double-buffered 256-col chunks (2x16KB);
// chunk-0 loads issue before QK (hidden), chunk c+1 loads during chunk c's PV.
// No-max softmax (scores <= ~7): p held in registers for the whole row => single
// pass writes normalized attn (nontemporal) and accumulates PV.
__global__ __launch_bounds__(1024, 1) void attn_fused_kernel(
    const float* __restrict__ qw, const float* __restrict__ kw, const float* __restrict__ vw,
    const int* __restrict__ adj, const float* __restrict__ sp,
    float* __restrict__ out, float* __restrict__ attn)
{
  __shared__ float sK[NTOK * DKH];        // 128KB
  __shared__ float sV[2][256 * DKH];      // 2 x 16KB double buffer
  float4* sK4 = (float4*)sK;

  const int phys = blockIdx.x;
  const int xcd  = phys & 7;
  const int slot = phys >> 3;             // 0..31
  const int G    = xcd * 4 + (slot >> 3); // 0..31 = rc*2 + b
  const int h    = slot & 7;
  const int rc   = G >> 1;
  const int b    = G & 1;
  const int bh   = b * NHEAD + h;
  const int t = threadIdx.x, lane = t & 63, w = t >> 6;

  const float*  Qp  = qw + (size_t)bh * NTOK * DKH;
  const float4* Kp4 = (const float4*)(kw + (size_t)bh * NTOK * DKH);
  const float4* Vp4 = (const float4*)(vw + (size_t)bh * NTOK * DKH);
  const int* adjb = adj + (size_t)b * NTOK * NTOK;
  float* attnb = attn + (size_t)bh * NTOK * NTOK;

  // Stage K for all 2048 cols (coalesced float4 reads, swizzled ds_write_b128)
  #pragma unroll
  for (int kk = 0; kk < 8; kk++) {
    int f4 = t + 1024 * kk;               // 8192 float4 total
    sK4[swzg(f4)] = Kp4[f4];
  }
  __syncthreads();

  for (int batch = 0; batch < 4; batch++) {
    const int r0 = rc * 128 + batch * 32 + w * 2;
    const int r1 = r0 + 1;

    // Issue V chunk-0 load now; completes under the whole QK phase.
    float4 pv = Vp4[t];

    float q0[16], q1[16];
    {
      const float4* q4a = (const float4*)(Qp + r0 * DKH);
      const float4* q4b = (const float4*)(Qp + r1 * DKH);
      float4 a0 = q4a[0], a1 = q4a[1], a2 = q4a[2], a3 = q4a[3];
      float4 c0v = q4b[0], c1 = q4b[1], c2 = q4b[2], c3 = q4b[3];
      q0[0]=a0.x; q0[1]=a0.y; q0[2]=a0.z; q0[3]=a0.w;
      q0[4]=a1.x; q0[5]=a1.y; q0[6]=a1.z; q0[7]=a1.w;
      q0[8]=a2.x; q0[9]=a2.y; q0[10]=a2.z; q0[11]=a2.w;
      q0[12]=a3.x; q0[13]=a3.y; q0[14]=a3.z; q0[15]=a3.w;
      q1[0]=c0v.x; q1[1]=c0v.y; q1[2]=c0v.z; q1[3]=c0v.w;
      q1[4]=c1.x; q1[5]=c1.y; q1[6]=c1.z; q1[7]=c1.w;
      q1[8]=c2.x; q1[9]=c2.y; q1[10]=c2.z; q1[11]=c2.w;
      q1[12]=c3.x; q1[13]=c3.y; q1[14]=c3.z; q1[15]=c3.w;
    }

    const float* sp0 = sp + (size_t)r0 * NTOK;
    const float* sp1 = sp + (size_t)r1 * NTOK;
    const int* a0p = adjb + (size_t)r0 * NTOK;
    const int* a1p = adjb + (size_t)r1 * NTOK;

    float p0[32], p1[32];
    float l0 = 0.f, l1 = 0.f;
    #pragma unroll
    for (int j = 0; j < 32; j++) {
      const int col = lane + 64 * j;
      const float4 k0 = sK4[swz(col, 0)], k1 = sK4[swz(col, 1)];
      const float4 k2 = sK4[swz(col, 2)], k3 = sK4[swz(col, 3)];
      float s0 = dot16(q0, k0, k1, k2, k3);
      float s1 = dot16(q1, k0, k1, k2, k3);
      float e0 = sp0[col]; if (col == r0) e0 = 0.f;   // sp_enc diagonal zeroed
      float e1 = sp1[col]; if (col == r1) e1 = 0.f;
      s0 = fmaf(s0, 0.25f, e0);                        // /sqrt(16)
      s1 = fmaf(s1, 0.25f, e1);
      const float pe0 = (a0p[col] != 0) ? __expf(s0) : 0.f;  // mask==exp(-1e10)==0
      const float pe1 = (a1p[col] != 0) ? __expf(s1) : 0.f;
      p0[j] = pe0; p1[j] = pe1;
      l0 += pe0; l1 += pe1;
    }

    #pragma unroll
    for (int m = 1; m < 64; m <<= 1) {
      l0 += __shfl_xor(l0, m, 64);
      l1 += __shfl_xor(l1, m, 64);
    }
    const float rl0 = 1.0f / l0, rl1 = 1.0f / l1;

    // Normalize IN PLACE: both the attn store and PV use softmax probabilities.
    // attn is write-once: nontemporal, don't pollute L2.
    float* A0 = attnb + (size_t)r0 * NTOK;
    float* A1 = attnb + (size_t)r1 * NTOK;
    #pragma unroll
    for (int j = 0; j < 32; j++) {
      p0[j] *= rl0;
      p1[j] *= rl1;
      __builtin_nontemporal_store(p0[j], &A0[lane + 64 * j]);
      __builtin_nontemporal_store(p1[j], &A1[lane + 64 * j]);
    }

    float o0[16], o1[16];
    #pragma unroll
    for (int d = 0; d < 16; d++) { o0[d] = 0.f; o1[d] = 0.f; }

    // Write chunk 0 (loaded above). buf0's last readers sat behind prev vc==6's
    // barrier, so it is free to overwrite.
    ((float4*)sV[0])[swzg(t)] = pv;
    __syncthreads();

    #pragma unroll
    for (int vc = 0; vc < 8; vc++) {
      float4 nv;
      if (vc < 7) nv = Vp4[(vc + 1) * 1024 + t];   // issue next chunk early
      const float4* sV4 = (const float4*)sV[vc & 1];
      #pragma unroll
      for (int jj = 0; jj < 4; jj++) {
        const int j = vc * 4 + jj;
        const int cl = lane + 64 * jj;
        const float4 v0 = sV4[swz(cl, 0)], v1 = sV4[swz(cl, 1)];
        const float4 v2 = sV4[swz(cl, 2)], v3 = sV4[swz(cl, 3)];
        const float a0 = p0[j], a1 = p1[j];
        o0[0] = fmaf(a0, v0.x, o0[0]);  o0[1] = fmaf(a0, v0.y, o0[1]);
        o0[2] = fmaf(a0, v0.z, o0[2]);  o0[3] = fmaf(a0, v0.w, o0[3]);
        o0[4] = fmaf(a0, v1.x, o0[4]);  o0[5] = fmaf(a0, v1.y, o0[5]);
        o0[6] = fmaf(a0, v1.z, o0[6]);  o0[7] = fmaf(a0, v1.w, o0[7]);
        o0[8] = fmaf(a0, v2.x, o0[8]);  o0[9] = fmaf(a0, v2.y, o0[9]);
        o0[10] = fmaf(a0, v2.z, o0[10]); o0[11] = fmaf(a0, v2.w, o0[11]);
        o0[12] = fmaf(a0, v3.x, o0[12]); o0[13] = fmaf(a0, v3.y, o0[13]);
        o0[14] = fmaf(a0, v3.z, o0[14]); o0[15] = fmaf(a0, v3.w, o0[15]);
        o1[0] = fmaf(a1, v0.x, o1[0]);  o1[1] = fmaf(a1, v0.y, o1[1]);
        o1[2] = fmaf(a1, v0.z, o1[2]);  o1[3] = fmaf(a1, v0.w, o1[3]);
        o1[4] = fmaf(a1, v1.x, o1[4]);  o1[5] = fmaf(a1, v1.y, o1[5]);
        o1[6] = fmaf(a1, v1.z, o1[6]);  o1[7] = fmaf(a1, v1.w, o1[7]);
        o1[8] = fmaf(a1, v2.x, o1[8]);  o1[9] = fmaf(a1, v2.y, o1[9]);
        o1[10] = fmaf(a1, v2.z, o1[10]); o1[11] = fmaf(a1, v2.w, o1[11]);
        o1[12] = fmaf(a1, v3.x, o1[12]); o1[13] = fmaf(a1, v3.y, o1[13]);
        o1[14] = fmaf(a1, v3.z, o1[14]); o1[15] = fmaf(a1, v3.w, o1[15]);
      }
      if (vc < 7) {
        ((float4*)sV[(vc + 1) & 1])[swzg(t)] = nv;
        __syncthreads();
      }
    }

    // cross-lane reduce the 2x16 partial outputs, lane 0 stores
    #pragma unroll
    for (int m = 1; m < 64; m <<= 1) {
      #pragma unroll
      for (int d = 0; d < 16; d++) {
        o0[d] += __shfl_xor(o0[d], m, 64);
        o1[d] += __shfl_xor(o1[d], m, 64);
      }
    }
    if (lane == 0) {
      #pragma unroll
      for (int d = 0; d < 16; d++) {
        // out layout: (b, n, dk, h) flattened -> [b][n][d*8 + h]
        out[((size_t)b * NTOK + r0) * DMODEL + d * NHEAD + h] = o0[d];
        out[((size_t)b * NTOK + r1) * DMODEL + d * NHEAD + h] = o1[d];
      }
    }
  }
}

extern "C" void kernel_launch(void* const* d_in, const int* in_sizes, int n_in,
                              void* d_out, int out_size, void* d_ws, size_t ws_size,
                              hipStream_t stream) {
  const float* x   = (const float*)d_in[0];
  const int*   adj = (const int*)d_in[1];
  const float* sp  = (const float*)d_in[2];
  const float* Wq  = (const float*)d_in[3];
  const float* bq  = (const float*)d_in[4];
  const float* Wk  = (const float*)d_in[5];
  const float* bk  = (const float*)d_in[6];
  const float* Wv  = (const float*)d_in[7];
  const float* bv  = (const float*)d_in[8];

  float* out  = (float*)d_out;
  float* attn = out + (size_t)BSZ * NTOK * DMODEL;
  float* ws   = (float*)d_ws;    // Q,K,V: 3 * 524288 floats = 6 MB

  qkv_proj_kernel<<<dim3(BSZ * NTOK / 32, 3), dim3(256), 0, stream>>>(
      x, Wq, bq, Wk, bk, Wv, bv, ws);

  const float* qws = ws;
  const float* kws = ws + (size_t)BSZ * NTOK * DMODEL;
  const float* vws = ws + (size_t)2 * BSZ * NTOK * DMODEL;
  attn_fused_kernel<<<dim3(256), dim3(1024), 0, stream>>>(
      qws, kws, vws, adj, sp, out, attn);
}

// Round 7
// 495.122 us; speedup vs baseline: 2.1140x; 2.0800x over previous
//
#include <hip/hip_runtime.h>

#define BSZ 2
#define NTOK 2048
#define NHEAD 8
#define DKH 16
#define DMODEL 128

// Swizzled float4 index for LDS tiles laid out [cols][16 floats].
// Row stride = 64B = 4 float4. Permute the 8 16B-granules inside each 128B
// col-pair: granule' = granule ^ ((col>>1)&7). Linear-granule closed form:
// g ^ ((g>>3)&7). Bijective (XOR key from untouched high bits).
__device__ __forceinline__ int swz(int col, int q4) {
  return ((col >> 1) << 3) | ((((col & 1) << 2) | q4) ^ ((col >> 1) & 7));
}
__device__ __forceinline__ int swzg(int g) { return g ^ ((g >> 3) & 7); }

__device__ __forceinline__ float dot16(const float (&q)[16], const float4& k0,
                                       const float4& k1, const float4& k2, const float4& k3) {
  float a = fmaf(q[3], k0.w, fmaf(q[2], k0.z, fmaf(q[1], k0.y, q[0] * k0.x)));
  float b = fmaf(q[7], k1.w, fmaf(q[6], k1.z, fmaf(q[5], k1.y, q[4] * k1.x)));
  float c = fmaf(q[11], k2.w, fmaf(q[10], k2.z, fmaf(q[9], k2.y, q[8] * k2.x)));
  float d = fmaf(q[15], k3.w, fmaf(q[14], k3.z, fmaf(q[13], k3.y, q[12] * k3.x)));  // r6 bug: was q[12]*k3.w
  return (a + b) + (c + d);
}

// ---------------- QKV projection (unchanged, passes) ----------------
__global__ __launch_bounds__(256) void qkv_proj_kernel(
    const float* __restrict__ x,
    const float* __restrict__ Wq, const float* __restrict__ bq,
    const float* __restrict__ Wk, const float* __restrict__ bk,
    const float* __restrict__ Wv, const float* __restrict__ bv,
    float* __restrict__ ws)
{
  __shared__ float sW[DMODEL * 32 * 4];   // [128][32] float4, swizzled, 64KB
  __shared__ float sX[32 * 32 * 4];       // [32][32]  float4, swizzled, 16KB
  const float *W, *bias;
  float* outp;
  if (blockIdx.y == 0)      { W = Wq; bias = bq; outp = ws; }
  else if (blockIdx.y == 1) { W = Wk; bias = bk; outp = ws + (size_t)BSZ * NTOK * DMODEL; }
  else                      { W = Wv; bias = bv; outp = ws + (size_t)2 * BSZ * NTOK * DMODEL; }

  const int t = threadIdx.x;
  float4* sW4 = (float4*)sW;
  float4* sX4 = (float4*)sX;
  #pragma unroll
  for (int k = 0; k < 16; k++) {
    int f4 = t + 256 * k;
    int o = f4 >> 5, i4 = f4 & 31;
    sW4[o * 32 + (i4 ^ (o & 7))] = ((const float4*)W)[f4];
  }
  #pragma unroll
  for (int k = 0; k < 4; k++) {
    int f4 = t + 256 * k;
    int r = f4 >> 5, i4 = f4 & 31;
    sX4[r * 32 + (i4 ^ (r & 7))] = ((const float4*)x)[(size_t)blockIdx.x * 1024 + f4];
  }
  __syncthreads();

  const int c0 = t & 31;
  const int r0 = t >> 5;
  float acc[4][4];
  #pragma unroll
  for (int i = 0; i < 4; i++)
    #pragma unroll
    for (int j = 0; j < 4; j++) acc[i][j] = 0.f;

  #pragma unroll 8
  for (int i0 = 0; i0 < 32; i0++) {
    float4 xr[4], wc[4];
    #pragma unroll
    for (int rr = 0; rr < 4; rr++) xr[rr] = sX4[(r0 + 8 * rr) * 32 + (i0 ^ (r0 & 7))];
    #pragma unroll
    for (int cc = 0; cc < 4; cc++) wc[cc] = sW4[(c0 + 32 * cc) * 32 + (i0 ^ (c0 & 7))];
    #pragma unroll
    for (int rr = 0; rr < 4; rr++)
      #pragma unroll
      for (int cc = 0; cc < 4; cc++) {
        acc[rr][cc] = fmaf(xr[rr].x, wc[cc].x, acc[rr][cc]);
        acc[rr][cc] = fmaf(xr[rr].y, wc[cc].y, acc[rr][cc]);
        acc[rr][cc] = fmaf(xr[rr].z, wc[cc].z, acc[rr][cc]);
        acc[rr][cc] = fmaf(xr[rr].w, wc[cc].w, acc[rr][cc]);
      }
  }

  #pragma unroll
  for (int cc = 0; cc < 4; cc++) {
    const int c = c0 + 32 * cc;
    const float bv_ = bias[c];
    const int hh = c >> 4, d = c & 15;
    #pragma unroll
    for (int rr = 0; rr < 4; rr++) {
      const int rg = blockIdx.x * 32 + r0 + 8 * rr;
      const int bb = rg >> 11, n = rg & (NTOK - 1);
      outp[(((size_t)(bb * NHEAD + hh)) * NTOK + n) * DKH + d] = acc[rr][cc] + bv_;
    }
  }
}

// ---------------- Fused attention v3: small blocks, streamed K+V ----------------
// 2048 blocks x 512 threads (8 waves); each block = one (b,h) x 16-row strip
// (wave = 2 rows). LDS = ONE 2x16KB double-buffer staging K chunks (QK phase)
// then V chunks (PV phase) -> 32KB total => 2 blocks/CU by LDS *and* by VGPR
// (~128) => 4 waves/SIMD, no spills (512-thr blocks proved 128 VGPR in r3;
// 1024-thr blocks pin to 64 VGPR + ~860MB spill traffic, r4/r5).
// K/V re-read per block from L2/L3 (K+V = 4MB total, L2-resident; aggregate
// ~0.5GB = ~15us of L2 BW). XCD-aware remap: all 16 blocks of one sp-row
// window (both b, all 8 h) on one XCD's L2.
// No-max softmax (scores <= ~7): p[2][32] in registers for the whole row =>
// single pass writes normalized attn (nontemporal) and accumulates PV.
__global__ __launch_bounds__(512, 2) void attn_fused_kernel(
    const float* __restrict__ qw, const float* __restrict__ kw, const float* __restrict__ vw,
    const int* __restrict__ adj, const float* __restrict__ sp,
    float* __restrict__ out, float* __restrict__ attn)
{
  __shared__ float4 sT[2][1024];          // 2 x 16KB staging (K phase, then V phase)

  const int phys = blockIdx.x;
  const int xcd  = phys & 7;              // HW round-robins consecutive ids over XCDs
  const int slot = phys >> 3;             // 0..255
  const int v    = ((slot >> 4) << 7) | (xcd << 4) | (slot & 15);  // bijective 0..2047
  const int rc   = v >> 4;                // row window 0..127
  const int bh   = v & 15;
  const int b    = bh >> 3;
  const int h    = bh & 7;
  const int t = threadIdx.x, lane = t & 63, w = t >> 6;

  const float*  Qp  = qw + (size_t)bh * NTOK * DKH;
  const float4* Kp4 = (const float4*)(kw + (size_t)bh * NTOK * DKH);
  const float4* Vp4 = (const float4*)(vw + (size_t)bh * NTOK * DKH);
  const int* adjb = adj + (size_t)b * NTOK * NTOK;
  float* attnb = attn + (size_t)bh * NTOK * NTOK;

  const int r0 = rc * 16 + w * 2;
  const int r1 = r0 + 1;

  // Issue K chunk-0 global loads immediately (16KB / 512 thr = 2 float4 each).
  float4 ka = Kp4[t], kb = Kp4[t + 512];

  float q0[16], q1[16];
  {
    const float4* q4a = (const float4*)(Qp + r0 * DKH);
    const float4* q4b = (const float4*)(Qp + r1 * DKH);
    float4 a0 = q4a[0], a1 = q4a[1], a2 = q4a[2], a3 = q4a[3];
    float4 c0v = q4b[0], c1 = q4b[1], c2 = q4b[2], c3 = q4b[3];
    q0[0]=a0.x; q0[1]=a0.y; q0[2]=a0.z; q0[3]=a0.w;
    q0[4]=a1.x; q0[5]=a1.y; q0[6]=a1.z; q0[7]=a1.w;
    q0[8]=a2.x; q0[9]=a2.y; q0[10]=a2.z; q0[11]=a2.w;
    q0[12]=a3.x; q0[13]=a3.y; q0[14]=a3.z; q0[15]=a3.w;
    q1[0]=c0v.x; q1[1]=c0v.y; q1[2]=c0v.z; q1[3]=c0v.w;
    q1[4]=c1.x; q1[5]=c1.y; q1[6]=c1.z; q1[7]=c1.w;
    q1[8]=c2.x; q1[9]=c2.y; q1[10]=c2.z; q1[11]=c2.w;
    q1[12]=c3.x; q1[13]=c3.y; q1[14]=c3.z; q1[15]=c3.w;
  }

  const float* sp0 = sp + (size_t)r0 * NTOK;
  const float* sp1 = sp + (size_t)r1 * NTOK;
  const int* a0p = adjb + (size_t)r0 * NTOK;
  const int* a1p = adjb + (size_t)r1 * NTOK;

  // ---- QK phase: 8 chunks of 256 cols, double-buffered ----
  ((float4*)sT[0])[swzg(t)] = ka;
  ((float4*)sT[0])[swzg(t + 512)] = kb;
  __syncthreads();

  float p0[32], p1[32];
  float l0 = 0.f, l1 = 0.f;
  #pragma unroll
  for (int vc = 0; vc < 8; vc++) {
    if (vc < 7) { ka = Kp4[(vc + 1) * 1024 + t]; kb = Kp4[(vc + 1) * 1024 + t + 512]; }
    const float4* s4 = (const float4*)sT[vc & 1];
    #pragma unroll
    for (int jj = 0; jj < 4; jj++) {
      const int j = vc * 4 + jj;
      const int cl = lane + 64 * jj;
      const int col = vc * 256 + cl;
      const float4 k0 = s4[swz(cl, 0)], k1 = s4[swz(cl, 1)];
      const float4 k2 = s4[swz(cl, 2)], k3 = s4[swz(cl, 3)];
      float s0 = dot16(q0, k0, k1, k2, k3);
      float s1 = dot16(q1, k0, k1, k2, k3);
      float e0 = sp0[col]; if (col == r0) e0 = 0.f;   // sp_enc diagonal zeroed
      float e1 = sp1[col]; if (col == r1) e1 = 0.f;
      s0 = fmaf(s0, 0.25f, e0);                        // /sqrt(16)
      s1 = fmaf(s1, 0.25f, e1);
      const float pe0 = (a0p[col] != 0) ? __expf(s0) : 0.f;  // mask==exp(-1e10)==0
      const float pe1 = (a1p[col] != 0) ? __expf(s1) : 0.f;
      p0[j] = pe0; p1[j] = pe1;
      l0 += pe0; l1 += pe1;
    }
    if (vc < 7) {
      float4* d4 = (float4*)sT[(vc + 1) & 1];
      d4[swzg(t)] = ka;
      d4[swzg(t + 512)] = kb;
      __syncthreads();
    }
  }

  // Issue V chunk-0 loads; they complete under softmax + attn stores.
  float4 va = Vp4[t], vb = Vp4[t + 512];

  #pragma unroll
  for (int m = 1; m < 64; m <<= 1) {
    l0 += __shfl_xor(l0, m, 64);
    l1 += __shfl_xor(l1, m, 64);
  }
  const float rl0 = 1.0f / l0, rl1 = 1.0f / l1;

  // Normalize IN PLACE: attn store and PV both use softmax probabilities.
  float* A0 = attnb + (size_t)r0 * NTOK;
  float* A1 = attnb + (size_t)r1 * NTOK;
  #pragma unroll
  for (int j = 0; j < 32; j++) {
    p0[j] *= rl0;
    p1[j] *= rl1;
    __builtin_nontemporal_store(p0[j], &A0[lane + 64 * j]);
    __builtin_nontemporal_store(p1[j], &A1[lane + 64 * j]);
  }

  // ---- PV phase: reuse sT. Writing sT[0] is safe: its last readers (vc==6)
  // are behind the vc==6 barrier, which every wave passed to reach vc==7.
  ((float4*)sT[0])[swzg(t)] = va;
  ((float4*)sT[0])[swzg(t + 512)] = vb;

  float o0[16], o1[16];
  #pragma unroll
  for (int d = 0; d < 16; d++) { o0[d] = 0.f; o1[d] = 0.f; }
  __syncthreads();

  #pragma unroll
  for (int vc = 0; vc < 8; vc++) {
    if (vc < 7) { va = Vp4[(vc + 1) * 1024 + t]; vb = Vp4[(vc + 1) * 1024 + t + 512]; }
    const float4* s4 = (const float4*)sT[vc & 1];
    #pragma unroll
    for (int jj = 0; jj < 4; jj++) {
      const int j = vc * 4 + jj;
      const int cl = lane + 64 * jj;
      const float4 v0 = s4[swz(cl, 0)], v1 = s4[swz(cl, 1)];
      const float4 v2 = s4[swz(cl, 2)], v3 = s4[swz(cl, 3)];
      const float a0 = p0[j], a1 = p1[j];
      o0[0] = fmaf(a0, v0.x, o0[0]);  o0[1] = fmaf(a0, v0.y, o0[1]);
      o0[2] = fmaf(a0, v0.z, o0[2]);  o0[3] = fmaf(a0, v0.w, o0[3]);
      o0[4] = fmaf(a0, v1.x, o0[4]);  o0[5] = fmaf(a0, v1.y, o0[5]);
      o0[6] = fmaf(a0, v1.z, o0[6]);  o0[7] = fmaf(a0, v1.w, o0[7]);
      o0[8] = fmaf(a0, v2.x, o0[8]);  o0[9] = fmaf(a0, v2.y, o0[9]);
      o0[10] = fmaf(a0, v2.z, o0[10]); o0[11] = fmaf(a0, v2.w, o0[11]);
      o0[12] = fmaf(a0, v3.x, o0[12]); o0[13] = fmaf(a0, v3.y, o0[13]);
      o0[14] = fmaf(a0, v3.z, o0[14]); o0[15] = fmaf(a0, v3.w, o0[15]);
      o1[0] = fmaf(a1, v0.x, o1[0]);  o1[1] = fmaf(a1, v0.y, o1[1]);
      o1[2] = fmaf(a1, v0.z, o1[2]);  o1[3] = fmaf(a1, v0.w, o1[3]);
      o1[4] = fmaf(a1, v1.x, o1[4]);  o1[5] = fmaf(a1, v1.y, o1[5]);
      o1[6] = fmaf(a1, v1.z, o1[6]);  o1[7] = fmaf(a1, v1.w, o1[7]);
      o1[8] = fmaf(a1, v2.x, o1[8]);  o1[9] = fmaf(a1, v2.y, o1[9]);
      o1[10] = fmaf(a1, v2.z, o1[10]); o1[11] = fmaf(a1, v2.w, o1[11]);
      o1[12] = fmaf(a1, v3.x, o1[12]); o1[13] = fmaf(a1, v3.y, o1[13]);
      o1[14] = fmaf(a1, v3.z, o1[14]); o1[15] = fmaf(a1, v3.w, o1[15]);
    }
    if (vc < 7) {
      float4* d4 = (float4*)sT[(vc + 1) & 1];
      d4[swzg(t)] = va;
      d4[swzg(t + 512)] = vb;
      __syncthreads();
    }
  }

  // cross-lane reduce the 2x16 partial outputs, lane 0 stores
  #pragma unroll
  for (int m = 1; m < 64; m <<= 1) {
    #pragma unroll
    for (int d = 0; d < 16; d++) {
      o0[d] += __shfl_xor(o0[d], m, 64);
      o1[d] += __shfl_xor(o1[d], m, 64);
    }
  }
  if (lane == 0) {
    #pragma unroll
    for (int d = 0; d < 16; d++) {
      // out layout: (b, n, dk, h) flattened -> [b][n][d*8 + h]
      out[((size_t)b * NTOK + r0) * DMODEL + d * NHEAD + h] = o0[d];
      out[((size_t)b * NTOK + r1) * DMODEL + d * NHEAD + h] = o1[d];
    }
  }
}

extern "C" void kernel_launch(void* const* d_in, const int* in_sizes, int n_in,
                              void* d_out, int out_size, void* d_ws, size_t ws_size,
                              hipStream_t stream) {
  const float* x   = (const float*)d_in[0];
  const int*   adj = (const int*)d_in[1];
  const float* sp  = (const float*)d_in[2];
  const float* Wq  = (const float*)d_in[3];
  const float* bq  = (const float*)d_in[4];
  const float* Wk  = (const float*)d_in[5];
  const float* bk  = (const float*)d_in[6];
  const float* Wv  = (const float*)d_in[7];
  const float* bv  = (const float*)d_in[8];

  float* out  = (float*)d_out;
  float* attn = out + (size_t)BSZ * NTOK * DMODEL;
  float* ws   = (float*)d_ws;    // Q,K,V: 3 * 524288 floats = 6 MB

  qkv_proj_kernel<<<dim3(BSZ * NTOK / 32, 3), dim3(256), 0, stream>>>(
      x, Wq, bq, Wk, bk, Wv, bv, ws);

  const float* qws = ws;
  const float* kws = ws + (size_t)BSZ * NTOK * DMODEL;
  const float* vws = ws + (size_t)2 * BSZ * NTOK * DMODEL;
  attn_fused_kernel<<<dim3(2048), dim3(512), 0, stream>>>(
      qws, kws, vws, adj, sp, out, attn);
}